// Round 4
// baseline (362.658 us; speedup 1.0000x reference)
//
#include <hip/hip_runtime.h>
#include <hip/hip_bf16.h>

// CombinedModel R4: single fused kernel.
//   Phase W: per-wave split-bf16 weight fragments from global (K0 folded in).
//   Phase A: gather, 8 lanes/point (coalesced 128B emb rows), 8 passes/block,
//            packed split-bf16 latent (hi|lo per dword) -> LDS (36.9 KB).
//   __syncthreads (single block-wide barrier).
//   Phase B: per-wave MFMA MLP (3-product split-bf16, L1/L2/L3), wave-private
//            packed h-buffer in LDS, wave_barrier-only ordering (R3-proven).
// Removes: 256 MB ws round-trip, 2 kernel launches, K0 serialization.

typedef __attribute__((ext_vector_type(2))) float f32x2;
typedef __attribute__((ext_vector_type(4))) float f32x4;
typedef __attribute__((ext_vector_type(4))) int   i32x4;
typedef __attribute__((ext_vector_type(8))) short s16x8;

#define GRID_W  2048
#define LSTR    36   // latent row stride (dwords): 144 B = 9*16 -> aligned b128, 2-way banks (free)
#define PSTR    68   // h-buffer row stride (dwords): 272 B = 17*16 -> aligned b128
#define SEL_HI  0x05040100u // v_perm: (lo16(b),lo16(a)) -> (hi(e0),hi(e1))
#define SEL_LO  0x07060302u // v_perm: (hi16(b),hi16(a)) -> (lo(e0),lo(e1))

static __device__ __forceinline__ unsigned bits_bf2(__hip_bfloat162 h) {
    union { __hip_bfloat162 b; unsigned u; } cv; cv.b = h; return cv.u;
}
// split (v0,v1) into bf16 hi + bf16 lo residual; packed dword_i = hi_i | lo_i<<16
static __device__ __forceinline__ void split2_packed(float v0, float v1, unsigned &p0, unsigned &p1) {
    float2 f; f.x = v0; f.y = v1;
    unsigned hu = bits_bf2(__float22bfloat162_rn(f));
    float2 d;
    d.x = v0 - __uint_as_float(hu << 16);
    d.y = v1 - __uint_as_float(hu & 0xffff0000u);
    unsigned lu = bits_bf2(__float22bfloat162_rn(d));
    p0 = (hu & 0xffffu) | (lu << 16);
    p1 = (hu >> 16) | (lu & 0xffff0000u);
}
static __device__ __forceinline__ void split_bf(float x, short &h, short &l) {
    unsigned u = __float_as_uint(x);
    unsigned r = (u + 0x7FFFu + ((u >> 16) & 1u)) & 0xFFFF0000u;
    h = (short)(r >> 16);
    float res = x - __uint_as_float(r);
    unsigned v = __float_as_uint(res);
    v += 0x7FFFu + ((v >> 16) & 1u);
    l = (short)(v >> 16);
}
static __device__ __forceinline__ void load_wfrag(const float* p, s16x8 &h, s16x8 &l) {
    f32x4 a = ((const f32x4*)p)[0];
    f32x4 b = ((const f32x4*)p)[1];
    float v[8] = {a.x, a.y, a.z, a.w, b.x, b.y, b.z, b.w};
#pragma unroll
    for (int j = 0; j < 8; ++j) { short hh, ll; split_bf(v[j], hh, ll); h[j] = hh; l[j] = ll; }
}
static __device__ __forceinline__ s16x8 unpack8(uint4 q0, uint4 q1, unsigned sel) {
    union { unsigned u[4]; s16x8 v; } r;
    r.u[0] = __builtin_amdgcn_perm(q0.y, q0.x, sel);
    r.u[1] = __builtin_amdgcn_perm(q0.w, q0.z, sel);
    r.u[2] = __builtin_amdgcn_perm(q1.y, q1.x, sel);
    r.u[3] = __builtin_amdgcn_perm(q1.w, q1.z, sel);
    return r.v;
}

__global__ __launch_bounds__(256, 2) void fused_all(
    const float* __restrict__ x,          // [N,2]
    const float* __restrict__ positions,  // [N_POS,2]
    const int*   __restrict__ nbmap,      // [H,W,4]
    const float* __restrict__ emb,        // [N_POS,32]
    const float* __restrict__ W1,         // [64,32]
    const float* __restrict__ b1,         // [64]
    const float* __restrict__ W2,         // [64,64]
    const float* __restrict__ b2,         // [64]
    const float* __restrict__ W3,         // [3,64]
    const float* __restrict__ b3,         // [3]
    const float* __restrict__ mu,         // [3]
    const float* __restrict__ sd,         // [3]
    float* __restrict__ out,              // [N,3]
    int npts)
{
    const int tid  = threadIdx.x;
    const int w    = tid >> 6;
    const int lid  = tid & 63;
    const int quad = lid >> 4;
    const int m16  = lid & 15;
    const int gbase = blockIdx.x * 256;

    __shared__ __align__(16) unsigned lat_lds[256 * LSTR];   // 36.9 KB packed latent
    __shared__ __align__(16) unsigned hbuf[4 * 16 * PSTR];   // 17.4 KB wave-private h

    // ---- Phase W: per-wave weight fragments (split bf16, VGPR-resident) ----
    // B-frag layout for 16x16x32: lane (quad,m16) holds B[k=quad*8+j][n=m16]
    s16x8 w1h[4], w1l[4];
#pragma unroll
    for (int nt = 0; nt < 4; ++nt)
        load_wfrag(W1 + (nt * 16 + m16) * 32 + quad * 8, w1h[nt], w1l[nt]);
    s16x8 w2h[2][4], w2l[2][4];
#pragma unroll
    for (int s = 0; s < 2; ++s)
#pragma unroll
        for (int nt = 0; nt < 4; ++nt)
            load_wfrag(W2 + (nt * 16 + m16) * 64 + s * 32 + quad * 8, w2h[s][nt], w2l[s][nt]);
    s16x8 w3h[2], w3l[2];
#pragma unroll
    for (int s = 0; s < 2; ++s) {
        if (m16 < 3) {
            load_wfrag(W3 + m16 * 64 + s * 32 + quad * 8, w3h[s], w3l[s]);
        } else {
            s16x8 z = {0, 0, 0, 0, 0, 0, 0, 0};
            w3h[s] = z; w3l[s] = z;
        }
    }
    float b1v[4], b2v[4];
#pragma unroll
    for (int nt = 0; nt < 4; ++nt) { b1v[nt] = b1[nt * 16 + m16]; b2v[nt] = b2[nt * 16 + m16]; }
    const int mm = (m16 < 3) ? m16 : 0;
    const float b3m = b3[mm], sdm = sd[mm], mum = mu[mm];

    // ---- Phase A: gather, 8 lanes per point, 8 passes per block ----
    {
        const int c = tid & 7;          // channel group: channels 4c..4c+3
        const int pr = tid >> 3;        // point-within-pass row (0..31)
#pragma unroll 2
        for (int pass = 0; pass < 8; ++pass) {
            const int pt = pass * 32 + pr;
            const int g = gbase + pt;
            if (g < npts) {
                f32x2 xv = ((const f32x2*)x)[g];
                int i0 = (int)xv.x, i1 = (int)xv.y;   // x >= 0: trunc == floor
                float f0 = (float)i0, f1 = (float)i1;
                i32x4 nb = ((const i32x4*)nbmap)[i0 * GRID_W + i1];
                int ids[4] = {nb.x, nb.y, nb.z, nb.w};
                float a0 = 0.f, a1 = 0.f, a2 = 0.f, a3 = 0.f;
#pragma unroll
                for (int k = 0; k < 4; ++k) {
                    f32x2 pp = ((const f32x2*)positions)[ids[k]];
                    float dx = pp.x - f0, dy = pp.y - f1;
                    float dist = sqrtf(dx * dx + dy * dy);
                    f32x4 e = *(const f32x4*)(emb + ids[k] * 32 + c * 4);
                    a0 = fmaf(dist, e.x, a0); a1 = fmaf(dist, e.y, a1);
                    a2 = fmaf(dist, e.z, a2); a3 = fmaf(dist, e.w, a3);
                }
                unsigned p0, p1, p2, p3;
                split2_packed(a0, a1, p0, p1);
                split2_packed(a2, a3, p2, p3);
                uint4 pv; pv.x = p0; pv.y = p1; pv.z = p2; pv.w = p3;
                *(uint4*)(lat_lds + pt * LSTR + c * 4) = pv;
            }
        }
    }
    __syncthreads();

    // ---- Phase B: per-wave MFMA MLP over 4 tiles of 16 points ----
    if (gbase + w * 64 >= npts) return;   // npts % 64 == 0; no further block barriers
    unsigned* hb = hbuf + w * 16 * PSTR;

#pragma unroll 1
    for (int t = 0; t < 4; ++t) {
        // A-frags from packed latent LDS
        const unsigned* ap = lat_lds + (w * 64 + t * 16 + m16) * LSTR + quad * 8;
        uint4 q0 = *(const uint4*)ap;
        uint4 q1 = *(const uint4*)(ap + 4);
        s16x8 ah = unpack8(q0, q1, SEL_HI);
        s16x8 al = unpack8(q0, q1, SEL_LO);

        // L1: latent[16x32] @ W1^T, split 3-product
        f32x4 c1[4];
#pragma unroll
        for (int nt = 0; nt < 4; ++nt) {
            f32x4 c = {0.f, 0.f, 0.f, 0.f};
            c = __builtin_amdgcn_mfma_f32_16x16x32_bf16(ah, w1l[nt], c, 0, 0, 0);
            c = __builtin_amdgcn_mfma_f32_16x16x32_bf16(al, w1h[nt], c, 0, 0, 0);
            c = __builtin_amdgcn_mfma_f32_16x16x32_bf16(ah, w1h[nt], c, 0, 0, 0);
            c1[nt] = c;
        }
        __builtin_amdgcn_wave_barrier();
#pragma unroll
        for (int nt = 0; nt < 4; ++nt)
#pragma unroll
            for (int r = 0; r < 4; r += 2) {
                float v0 = fmaxf(c1[nt][r]     + b1v[nt], 0.f);
                float v1 = fmaxf(c1[nt][r + 1] + b1v[nt], 0.f);
                unsigned p0, p1; split2_packed(v0, v1, p0, p1);
                hb[(quad * 4 + r)     * PSTR + nt * 16 + m16] = p0;
                hb[(quad * 4 + r + 1) * PSTR + nt * 16 + m16] = p1;
            }
        __builtin_amdgcn_wave_barrier();

        // L2: h1[16x64] @ W2^T, split 3-product
        f32x4 c2[4] = {{0.f,0.f,0.f,0.f},{0.f,0.f,0.f,0.f},{0.f,0.f,0.f,0.f},{0.f,0.f,0.f,0.f}};
#pragma unroll
        for (int s = 0; s < 2; ++s) {
            const unsigned* rp = hb + m16 * PSTR + s * 32 + quad * 8;
            uint4 h0 = *(const uint4*)rp;
            uint4 h1 = *(const uint4*)(rp + 4);
            s16x8 a2h = unpack8(h0, h1, SEL_HI);
            s16x8 a2l = unpack8(h0, h1, SEL_LO);
#pragma unroll
            for (int nt = 0; nt < 4; ++nt) {
                c2[nt] = __builtin_amdgcn_mfma_f32_16x16x32_bf16(a2h, w2l[s][nt], c2[nt], 0, 0, 0);
                c2[nt] = __builtin_amdgcn_mfma_f32_16x16x32_bf16(a2l, w2h[s][nt], c2[nt], 0, 0, 0);
                c2[nt] = __builtin_amdgcn_mfma_f32_16x16x32_bf16(a2h, w2h[s][nt], c2[nt], 0, 0, 0);
            }
        }
        __builtin_amdgcn_wave_barrier();
        // h2 -> same wave-private buffer (DS pipe in-order within wave)
#pragma unroll
        for (int nt = 0; nt < 4; ++nt)
#pragma unroll
            for (int r = 0; r < 4; r += 2) {
                float v0 = fmaxf(c2[nt][r]     + b2v[nt], 0.f);
                float v1 = fmaxf(c2[nt][r + 1] + b2v[nt], 0.f);
                unsigned p0, p1; split2_packed(v0, v1, p0, p1);
                hb[(quad * 4 + r)     * PSTR + nt * 16 + m16] = p0;
                hb[(quad * 4 + r + 1) * PSTR + nt * 16 + m16] = p1;
            }
        __builtin_amdgcn_wave_barrier();

        // L3: h2[16x64] @ W3p^T (rows 0..2 valid), split 3-product
        f32x4 c3 = {0.f, 0.f, 0.f, 0.f};
#pragma unroll
        for (int s = 0; s < 2; ++s) {
            const unsigned* rp = hb + m16 * PSTR + s * 32 + quad * 8;
            uint4 h0 = *(const uint4*)rp;
            uint4 h1 = *(const uint4*)(rp + 4);
            s16x8 a3h = unpack8(h0, h1, SEL_HI);
            s16x8 a3l = unpack8(h0, h1, SEL_LO);
            c3 = __builtin_amdgcn_mfma_f32_16x16x32_bf16(a3h, w3l[s], c3, 0, 0, 0);
            c3 = __builtin_amdgcn_mfma_f32_16x16x32_bf16(a3l, w3h[s], c3, 0, 0, 0);
            c3 = __builtin_amdgcn_mfma_f32_16x16x32_bf16(a3h, w3h[s], c3, 0, 0, 0);
        }
        __builtin_amdgcn_wave_barrier();
#pragma unroll
        for (int r = 0; r < 4; ++r) {
            float v = (c3[r] + b3m) * sdm + mum;
            v = fminf(fmaxf(v, 0.f), 1.f);   // finite inputs: no NaN path
            if (m16 < 3) out[(size_t)(gbase + w * 64 + t * 16 + quad * 4 + r) * 3 + m16] = v;
        }
        __builtin_amdgcn_wave_barrier();
    }
}

extern "C" void kernel_launch(void* const* d_in, const int* in_sizes, int n_in,
                              void* d_out, int out_size, void* d_ws, size_t ws_size,
                              hipStream_t stream) {
    const float* x         = (const float*)d_in[0];
    const float* positions = (const float*)d_in[1];
    const int*   nbmap     = (const int*)d_in[2];
    const float* emb       = (const float*)d_in[3];
    const float* W1        = (const float*)d_in[4];
    const float* b1        = (const float*)d_in[5];
    const float* W2        = (const float*)d_in[6];
    const float* b2        = (const float*)d_in[7];
    const float* W3        = (const float*)d_in[8];
    const float* b3        = (const float*)d_in[9];
    const float* mu        = (const float*)d_in[10];
    const float* sd        = (const float*)d_in[11];
    float* out = (float*)d_out;

    int npts = in_sizes[0] / 2;
    int blocks = (npts + 255) / 256;
    fused_all<<<blocks, 256, 0, stream>>>(x, positions, nbmap, emb,
                                          W1, b1, W2, b2, W3, b3, mu, sd,
                                          out, npts);
}